// Round 11
// baseline (237.771 us; speedup 1.0000x reference)
//
#include <hip/hip_runtime.h>
#include <hip/hip_fp16.h>

typedef _Float16 f16x8 __attribute__((ext_vector_type(8)));
typedef __fp16   fp16x2 __attribute__((ext_vector_type(2)));   // cvt_pkrtz return type
typedef float f32x4 __attribute__((ext_vector_type(4)));

#define FEAT 44
#define TED  84
#define MT   128     // nodes per tile (block)
#define WN   32      // nodes per wave
#define NBLK 768     // persistent blocks (3 per CU)
#define BUFB 6144    // per-wave staging buffer bytes (attr 5632 used; A1 [0,4096), A2 [4096,6144))
#define NREP 4       // measurement probe: main work repeated 4x (idempotent writes)

// ---------------- kernel 0: per-node graph id (expand ptr) ----------------
__global__ void seg_prep(const int* __restrict__ gptr, int* __restrict__ seg) {
    int g = blockIdx.x;
    int a = gptr[g], b = gptr[g + 1];
    for (int i = a + threadIdx.x; i < b; i += 256) seg[i] = g;
}

// ---------------- kernel 1: per-graph emb0 = swish(embed) @ w0[:,44:]^T + b0 ; inv_std; weights ----------------
__global__ void embed_prep(const float* __restrict__ t_arr, const float* __restrict__ W_f,
                           const float* __restrict__ embed_w, const float* __restrict__ embed_b,
                           const float* __restrict__ w0, const float* __restrict__ b0,
                           const float* __restrict__ w1, const float* __restrict__ w2,
                           float* __restrict__ emb0, float* __restrict__ inv_std,
                           _Float16* __restrict__ w0h, _Float16* __restrict__ w1h,
                           _Float16* __restrict__ w2h, int B) {
    int g   = blockIdx.x;
    int tid = threadIdx.x;
    if (g == B) {   // weight repack block: w0h = [64 out][64 in] (cols 44..63 zero)
        for (int i = tid; i < 64 * 64; i += 128) {
            int o = i >> 6, k = i & 63;
            w0h[i] = (k < FEAT) ? (_Float16)w0[o * 128 + k] : (_Float16)0.f;
        }
        for (int i = tid; i < 32 * 64; i += 128) w1h[i] = (_Float16)w1[i];
        for (int i = tid; i < 16 * 32; i += 128) w2h[i] = (i < 4 * 32) ? (_Float16)w2[i] : (_Float16)0.f;
        return;
    }
    __shared__ float temb[TED];
    __shared__ float ses[TED];
    float tv = t_arr[g];
    if (tid < TED) {
        int j   = (tid < TED / 2) ? tid : tid - TED / 2;
        float x = tv * W_f[j] * 6.283185307179586f;
        temb[tid] = (tid < TED / 2) ? sinf(x) : cosf(x);
    }
    __syncthreads();
    if (tid < TED) {
        const float* wr = embed_w + tid * TED;
        float s = embed_b[tid];
        #pragma unroll 4
        for (int j = 0; j < TED; ++j) s = fmaf(temb[j], wr[j], s);
        ses[tid] = s / (1.0f + __expf(-s));
    }
    if (tid == TED) {
        const float c = 6.437751649736401f;      // 2*ln(25)
        inv_std[g] = rsqrtf(expm1f(c * tv) / c);
    }
    __syncthreads();
    if (tid < 64) {
        const float* wr = w0 + tid * 128 + FEAT;   // w0[tid][44..127]
        float s = b0[tid];
        #pragma unroll 4
        for (int j = 0; j < TED; ++j) s = fmaf(ses[j], wr[j], s);
        emb0[g * 64 + tid] = s;
    }
}

// ---------------- kernel 2: persistent fused MLP, LDS-staged cross-tile pipeline ----------------
__device__ __forceinline__ float swishf(float x) {
    float e = __builtin_amdgcn_exp2f(x * -1.4426950408889634f);
    return x * __builtin_amdgcn_rcpf(1.0f + e);
}

__device__ __forceinline__ int ubound(const int* __restrict__ p, int n, int v) {
    int lo = 0, hi = n;
    while (lo < hi) { int m = (lo + hi) >> 1; if (p[m] <= v) lo = m + 1; else hi = m; }
    return lo - 1;
}

// 6 x global_load_lds(16B): stages 6144B (5632 valid) of node_attr into wave-uniform LDS dst.
__device__ __forceinline__ void stage_attr(const float* __restrict__ node_attr, int row0,
                                           const char* lim, char* dst, int lane) {
    const char* g = (const char*)node_attr + (size_t)row0 * (FEAT * 4);
    #pragma unroll
    for (int k = 0; k < 6; ++k) {
        const char* s = g + k * 1024 + lane * 16;
        if (s > lim) s = lim;                     // clamp: pad lanes read safe bytes
        __builtin_amdgcn_global_load_lds(
            (const __attribute__((address_space(1))) unsigned int*)s,
            (__attribute__((address_space(3))) unsigned int*)(dst + k * 1024),
            16, 0, 0);
    }
}

template<bool USE_SEG>
__global__ __launch_bounds__(256)
void scorenet_main(const float* __restrict__ node_attr,
                   const int* __restrict__ gptr, int B,
                   const int* __restrict__ seg_arr,
                   const float* __restrict__ emb0,
                   const float* __restrict__ inv_std_g,
                   const _Float16* __restrict__ w0h,
                   const _Float16* __restrict__ w1h,
                   const _Float16* __restrict__ w2h,
                   const float* __restrict__ b1,
                   const float* __restrict__ b2,
                   float* __restrict__ out, int ntiles, int nbytes_attr) {
    __shared__ __align__(16) char lds[2 * BUFB * 4];

    const int t    = threadIdx.x;
    const int lane = t & 63;
    const int wid  = t >> 6;
    const int lr   = lane & 15;
    const int lk   = lane >> 4;
    const char* lim = (const char*)node_attr + nbytes_attr - 16;

    if (blockIdx.x >= ntiles) return;
    const int stride = gridDim.x;

    // ---- ALL tile-invariant weights resident (no in-loop VMEM except tile data) ----
    f16x8 aw0[2][4];                          // [kt][mt], A row = out-feat mt*16+lr
    #pragma unroll
    for (int kt = 0; kt < 2; ++kt)
        #pragma unroll
        for (int mt = 0; mt < 4; ++mt)
            aw0[kt][mt] = *(const f16x8*)(w0h + (mt * 16 + lr) * 64 + kt * 32 + lk * 8);
    f16x8 aw1[2][2];
    #pragma unroll
    for (int kt = 0; kt < 2; ++kt)
        #pragma unroll
        for (int mt = 0; mt < 2; ++mt)
            aw1[kt][mt] = *(const f16x8*)(w1h + (mt * 16 + lr) * 64 + kt * 32 + lk * 8);
    f16x8 aw2 = *(const f16x8*)(w2h + lr * 32 + lk * 8);
    f32x4 bias1f[2];
    #pragma unroll
    for (int mt = 0; mt < 2; ++mt) {
        float4 bv = *(const float4*)(b1 + mt * 16 + lk * 4);
        bias1f[mt] = f32x4{bv.x, bv.y, bv.z, bv.w};
    }
    float4 b2vv = *(const float4*)b2;
    const f32x4 c2init = (lk == 0) ? f32x4{b2vv.x, b2vv.y, b2vv.z, b2vv.w} : f32x4{0.f, 0.f, 0.f, 0.f};

    char* buf0 = lds + wid * (2 * BUFB);

    for (int rep = 0; rep < NREP; ++rep) {
        char* buf_cur = buf0;
        char* buf_nxt = buf0 + BUFB;
        int tile = blockIdx.x;

        // ---- prologue: stage tile0 + its seg ----
        stage_attr(node_attr, tile * MT + wid * WN, lim, buf_cur, lane);
        int seg0, seg1;
        {
            int wb = tile * MT + wid * WN;
            if (USE_SEG) { seg0 = seg_arr[wb + lr]; seg1 = seg_arr[wb + 16 + lr]; }
            else { seg0 = ubound(gptr, B + 1, wb + lr); seg1 = ubound(gptr, B + 1, wb + 16 + lr); }
        }

        while (tile < ntiles) {
            const int wb   = tile * MT + wid * WN;
            int tpf = tile + stride; if (tpf >= ntiles) tpf = tile;   // clamp: branchless tail
            const int nwb  = tpf * MT + wid * WN;

            // ---- A: current tile gathers FIRST (10 VMEM; their wait leaves B,C in flight) ----
            float is0 = inv_std_g[seg0];
            float is1 = inv_std_g[seg1];
            f32x4 acc0[4][2];
            #pragma unroll
            for (int mt = 0; mt < 4; ++mt) {
                acc0[mt][0] = *(const f32x4*)(emb0 + seg0 * 64 + mt * 16 + lk * 4);
                acc0[mt][1] = *(const f32x4*)(emb0 + seg1 * 64 + mt * 16 + lk * 4);
            }

            // ---- B: stage next tile -> buf_nxt (6 VMEM, zero VGPR, stays in flight all iter) ----
            stage_attr(node_attr, nwb, lim, buf_nxt, lane);

            // ---- C: next tile's seg (2 VMEM, awaited at next iteration's top) ----
            int ns0, ns1;
            if (USE_SEG) { ns0 = seg_arr[nwb + lr]; ns1 = seg_arr[nwb + 16 + lr]; }
            else { ns0 = ubound(gptr, B + 1, nwb + lr); ns1 = ubound(gptr, B + 1, nwb + 16 + lr); }

            // ---- drain anything older than the 18 loads above (prev-iter stage of buf_cur) ----
            asm volatile("s_waitcnt vmcnt(18)" ::: "memory");
            __builtin_amdgcn_sched_barrier(0);

            // ---- cvt: read this tile's attr from buf_cur (f32) -> L0 B-fragments (f16) ----
            union u8 { fp16x2 h2[4]; f16x8 v; };
            f16x8 bf[2][2];
            #pragma unroll
            for (int nt = 0; nt < 2; ++nt) {
                const float4* rowp = (const float4*)(buf_cur + (nt * 16 + lr) * (FEAT * 4));
                float4 a = rowp[lk * 2];
                float4 b = rowp[lk * 2 + 1];
                float4 c = make_float4(0.f, 0.f, 0.f, 0.f);
                float4 d = make_float4(0.f, 0.f, 0.f, 0.f);
                if (lk == 0) { c = rowp[8]; d = rowp[9]; }        // feats 32..39
                else if (lk == 1) { c = rowp[10]; }               // feats 40..43 (44..47 zero)
                u8 f0, f1;
                f0.h2[0] = __builtin_amdgcn_cvt_pkrtz(a.x, a.y);
                f0.h2[1] = __builtin_amdgcn_cvt_pkrtz(a.z, a.w);
                f0.h2[2] = __builtin_amdgcn_cvt_pkrtz(b.x, b.y);
                f0.h2[3] = __builtin_amdgcn_cvt_pkrtz(b.z, b.w);
                f1.h2[0] = __builtin_amdgcn_cvt_pkrtz(c.x, c.y);
                f1.h2[1] = __builtin_amdgcn_cvt_pkrtz(c.z, c.w);
                f1.h2[2] = __builtin_amdgcn_cvt_pkrtz(d.x, d.y);
                f1.h2[3] = __builtin_amdgcn_cvt_pkrtz(d.z, d.w);
                bf[nt][0] = f0.v;
                bf[nt][1] = f1.v;
            }

            // ---- layer 0: D^T[64 out][32 nodes], K=64, C-init = emb0 (wait = vmcnt(8)) ----
            #pragma unroll
            for (int kt = 0; kt < 2; ++kt)
                #pragma unroll
                for (int mt = 0; mt < 4; ++mt)
                    #pragma unroll
                    for (int nt = 0; nt < 2; ++nt)
                        acc0[mt][nt] = __builtin_amdgcn_mfma_f32_16x16x32_f16(aw0[kt][mt], bf[nt][kt], acc0[mt][nt], 0, 0, 0);

            // ---- epilogue 0 -> A1 in buf_cur [0,4096) (attr consumed; same-wave DS order) ----
            #pragma unroll
            for (int mt = 0; mt < 4; ++mt)
                #pragma unroll
                for (int nt = 0; nt < 2; ++nt) {
                    int j = nt * 16 + lr;
                    union { fp16x2 h2[2]; uint2 u; } p;
                    p.h2[0] = __builtin_amdgcn_cvt_pkrtz(swishf(acc0[mt][nt][0]), swishf(acc0[mt][nt][1]));
                    p.h2[1] = __builtin_amdgcn_cvt_pkrtz(swishf(acc0[mt][nt][2]), swishf(acc0[mt][nt][3]));
                    int addr = j * 128 + (mt * 16 + lk * 4) * 2;
                    *(uint2*)(buf_cur + (addr ^ ((j & 7) << 4))) = p.u;
                }

            // ---- layer 1: D^T[32 out][32 nodes], K=64, C-init = b1 (registers, no VMEM) ----
            f32x4 acc1[2][2];
            #pragma unroll
            for (int mt = 0; mt < 2; ++mt) { acc1[mt][0] = bias1f[mt]; acc1[mt][1] = bias1f[mt]; }
            #pragma unroll
            for (int kt = 0; kt < 2; ++kt) {
                f16x8 bx[2];
                #pragma unroll
                for (int nt = 0; nt < 2; ++nt) {
                    int j    = nt * 16 + lr;
                    int addr = j * 128 + kt * 64 + lk * 16;
                    bx[nt] = *(const f16x8*)(buf_cur + (addr ^ ((j & 7) << 4)));
                }
                #pragma unroll
                for (int mt = 0; mt < 2; ++mt)
                    #pragma unroll
                    for (int nt = 0; nt < 2; ++nt)
                        acc1[mt][nt] = __builtin_amdgcn_mfma_f32_16x16x32_f16(aw1[kt][mt], bx[nt], acc1[mt][nt], 0, 0, 0);
            }

            // ---- epilogue 1 -> A2 in buf_cur [4096,6144), 64B rows ----
            #pragma unroll
            for (int mt = 0; mt < 2; ++mt)
                #pragma unroll
                for (int nt = 0; nt < 2; ++nt) {
                    int j = nt * 16 + lr;
                    union { fp16x2 h2[2]; uint2 u; } p;
                    p.h2[0] = __builtin_amdgcn_cvt_pkrtz(swishf(acc1[mt][nt][0]), swishf(acc1[mt][nt][1]));
                    p.h2[1] = __builtin_amdgcn_cvt_pkrtz(swishf(acc1[mt][nt][2]), swishf(acc1[mt][nt][3]));
                    int addr = 4096 + j * 64 + (mt * 16 + lk * 4) * 2;
                    *(uint2*)(buf_cur + (addr ^ ((j & 3) << 4))) = p.u;
                }

            // ---- layer 2 + direct global store ----
            f32x4 acc2[2] = {c2init, c2init};
            #pragma unroll
            for (int nt = 0; nt < 2; ++nt) {
                int j    = nt * 16 + lr;
                int addr = 4096 + j * 64 + lk * 16;
                f16x8 bx = *(const f16x8*)(buf_cur + (addr ^ ((j & 3) << 4)));
                acc2[nt] = __builtin_amdgcn_mfma_f32_16x16x32_f16(aw2, bx, acc2[nt], 0, 0, 0);
            }
            if (lk == 0) {
                #pragma unroll
                for (int nt = 0; nt < 2; ++nt) {
                    int j = nt * 16 + lr;
                    float is = nt ? is1 : is0;
                    float4 o;
                    o.x = swishf(acc2[nt][0]) * is;
                    o.y = swishf(acc2[nt][1]) * is;
                    o.z = swishf(acc2[nt][2]) * is;
                    o.w = swishf(acc2[nt][3]) * is;
                    *(float4*)(out + (size_t)(wb + j) * 4) = o;
                }
            }

            // ---- rotate pipeline ----
            { char* tmp = buf_cur; buf_cur = buf_nxt; buf_nxt = tmp; }
            seg0 = ns0; seg1 = ns1;
            tile += stride;
        }
    }
}

// ---------------- launch ----------------
extern "C" void kernel_launch(void* const* d_in, const int* in_sizes, int n_in,
                              void* d_out, int out_size, void* d_ws, size_t ws_size,
                              hipStream_t stream) {
    const float* node_attr = (const float*)d_in[0];
    const float* t_arr     = (const float*)d_in[1];
    const int*   gptr      = (const int*)d_in[2];
    const float* W_f       = (const float*)d_in[3];
    const float* embed_w   = (const float*)d_in[4];
    const float* embed_b   = (const float*)d_in[5];
    const float* w0        = (const float*)d_in[6];
    const float* b0        = (const float*)d_in[7];
    const float* w1        = (const float*)d_in[8];
    const float* b1        = (const float*)d_in[9];
    const float* w2        = (const float*)d_in[10];
    const float* b2        = (const float*)d_in[11];
    float* out = (float*)d_out;

    const int N = in_sizes[0] / FEAT;
    const int B = in_sizes[2] - 1;
    const int ntiles = N / MT;
    const int nbytes_attr = in_sizes[0] * 4;

    char* ws = (char*)d_ws;
    size_t off = 0;
    float*    emb0    = (float*)(ws + off); off += (size_t)B * 64 * sizeof(float);
    off = (off + 1023) & ~(size_t)1023;
    float*    inv_std = (float*)(ws + off); off += (size_t)B * sizeof(float);
    off = (off + 1023) & ~(size_t)1023;
    _Float16* w0h = (_Float16*)(ws + off);  off += 64 * 64 * sizeof(_Float16);
    _Float16* w1h = (_Float16*)(ws + off);  off += 32 * 64 * sizeof(_Float16);
    _Float16* w2h = (_Float16*)(ws + off);  off += 16 * 32 * sizeof(_Float16);
    off = (off + 1023) & ~(size_t)1023;
    int* seg = (int*)(ws + off);
    size_t need_with_seg = off + (size_t)N * sizeof(int);
    bool use_seg = (ws_size >= need_with_seg);

    const int grid = (ntiles < NBLK) ? ntiles : NBLK;

    embed_prep<<<B + 1, 128, 0, stream>>>(t_arr, W_f, embed_w, embed_b, w0, b0, w1, w2,
                                          emb0, inv_std, w0h, w1h, w2h, B);
    if (use_seg) {
        seg_prep<<<B, 256, 0, stream>>>(gptr, seg);
        scorenet_main<true><<<grid, 256, 0, stream>>>(node_attr, gptr, B, seg, emb0, inv_std,
                                                      w0h, w1h, w2h, b1, b2, out, ntiles, nbytes_attr);
    } else {
        scorenet_main<false><<<grid, 256, 0, stream>>>(node_attr, gptr, B, seg, emb0, inv_std,
                                                       w0h, w1h, w2h, b1, b2, out, ntiles, nbytes_attr);
    }
}

// Round 12
// 83.828 us; speedup vs baseline: 2.8364x; 2.8364x over previous
//
#include <hip/hip_runtime.h>
#include <hip/hip_fp16.h>

typedef _Float16 f16x8 __attribute__((ext_vector_type(8)));
typedef __fp16   fp16x2 __attribute__((ext_vector_type(2)));   // cvt_pkrtz return type
typedef float f32x4 __attribute__((ext_vector_type(4)));

#define FEAT 44
#define TED  84
#define MT   128     // nodes per tile (block)
#define WN   32      // nodes per wave
#define NBLK 768     // persistent blocks (3 per CU)
#define BUFB 6144    // per-wave staging buffer bytes (attr 5632 used; A1 [0,4096), A2 [4096,6144))

// ---------------- kernel 1: merged prep ----------------
// block g < B: seg fill + Fourier embed + emb0 = swish(embed)@w0[:,44:]^T + b0 + inv_std
// block g == B: weight repack
__global__ void prep_all(const float* __restrict__ t_arr, const float* __restrict__ W_f,
                         const float* __restrict__ embed_w, const float* __restrict__ embed_b,
                         const float* __restrict__ w0, const float* __restrict__ b0,
                         const float* __restrict__ w1, const float* __restrict__ w2,
                         const int* __restrict__ gptr, int* __restrict__ seg, int do_seg,
                         float* __restrict__ emb0, float* __restrict__ inv_std,
                         _Float16* __restrict__ w0h, _Float16* __restrict__ w1h,
                         _Float16* __restrict__ w2h, int B) {
    int g   = blockIdx.x;
    int tid = threadIdx.x;
    if (g == B) {   // weight repack block: w0h = [64 out][64 in] (cols 44..63 zero)
        for (int i = tid; i < 64 * 64; i += 128) {
            int o = i >> 6, k = i & 63;
            w0h[i] = (k < FEAT) ? (_Float16)w0[o * 128 + k] : (_Float16)0.f;
        }
        for (int i = tid; i < 32 * 64; i += 128) w1h[i] = (_Float16)w1[i];
        for (int i = tid; i < 16 * 32; i += 128) w2h[i] = (i < 4 * 32) ? (_Float16)w2[i] : (_Float16)0.f;
        return;
    }
    // seg fill (independent; before barriers so it overlaps)
    if (do_seg) {
        int a = gptr[g], b = gptr[g + 1];
        for (int i = a + tid; i < b; i += 128) seg[i] = g;
    }
    __shared__ float temb[TED];
    __shared__ float ses[TED];
    float tv = t_arr[g];
    if (tid < TED) {
        int j   = (tid < TED / 2) ? tid : tid - TED / 2;
        float x = tv * W_f[j] * 6.283185307179586f;
        temb[tid] = (tid < TED / 2) ? sinf(x) : cosf(x);
    }
    __syncthreads();
    if (tid < TED) {
        const float* wr = embed_w + tid * TED;
        float s = embed_b[tid];
        #pragma unroll 4
        for (int j = 0; j < TED; ++j) s = fmaf(temb[j], wr[j], s);
        ses[tid] = s / (1.0f + __expf(-s));
    }
    if (tid == TED) {
        const float c = 6.437751649736401f;      // 2*ln(25)
        inv_std[g] = rsqrtf(expm1f(c * tv) / c);
    }
    __syncthreads();
    if (tid < 64) {
        const float* wr = w0 + tid * 128 + FEAT;   // w0[tid][44..127]
        float s = b0[tid];
        #pragma unroll 4
        for (int j = 0; j < TED; ++j) s = fmaf(ses[j], wr[j], s);
        emb0[g * 64 + tid] = s;
    }
}

// ---------------- kernel 2: persistent fused MLP, LDS-staged pipeline, seg depth-2 ----------------
__device__ __forceinline__ float swishf(float x) {
    float e = __builtin_amdgcn_exp2f(x * -1.4426950408889634f);
    return x * __builtin_amdgcn_rcpf(1.0f + e);
}

__device__ __forceinline__ int ubound(const int* __restrict__ p, int n, int v) {
    int lo = 0, hi = n;
    while (lo < hi) { int m = (lo + hi) >> 1; if (p[m] <= v) lo = m + 1; else hi = m; }
    return lo - 1;
}

// 6 x global_load_lds(16B): stages 6144B (5632 valid) of node_attr into wave-uniform LDS dst.
__device__ __forceinline__ void stage_attr(const float* __restrict__ node_attr, int row0,
                                           const char* lim, char* dst, int lane) {
    const char* g = (const char*)node_attr + (size_t)row0 * (FEAT * 4);
    #pragma unroll
    for (int k = 0; k < 6; ++k) {
        const char* s = g + k * 1024 + lane * 16;
        if (s > lim) s = lim;                     // clamp: pad lanes read safe bytes
        __builtin_amdgcn_global_load_lds(
            (const __attribute__((address_space(1))) unsigned int*)s,
            (__attribute__((address_space(3))) unsigned int*)(dst + k * 1024),
            16, 0, 0);
    }
}

template<bool USE_SEG>
__global__ __launch_bounds__(256)
void scorenet_main(const float* __restrict__ node_attr,
                   const int* __restrict__ gptr, int B,
                   const int* __restrict__ seg_arr,
                   const float* __restrict__ emb0,
                   const float* __restrict__ inv_std_g,
                   const _Float16* __restrict__ w0h,
                   const _Float16* __restrict__ w1h,
                   const _Float16* __restrict__ w2h,
                   const float* __restrict__ b1,
                   const float* __restrict__ b2,
                   float* __restrict__ out, int ntiles, int nbytes_attr) {
    __shared__ __align__(16) char lds[2 * BUFB * 4];

    const int t    = threadIdx.x;
    const int lane = t & 63;
    const int wid  = t >> 6;
    const int lr   = lane & 15;
    const int lk   = lane >> 4;
    const char* lim = (const char*)node_attr + nbytes_attr - 16;

    if (blockIdx.x >= ntiles) return;
    const int stride = gridDim.x;

    // ---- tile-invariant weights resident ----
    f16x8 aw0[2][4];                          // [kt][mt], A row = out-feat mt*16+lr
    #pragma unroll
    for (int kt = 0; kt < 2; ++kt)
        #pragma unroll
        for (int mt = 0; mt < 4; ++mt)
            aw0[kt][mt] = *(const f16x8*)(w0h + (mt * 16 + lr) * 64 + kt * 32 + lk * 8);
    f16x8 aw1[2][2];
    #pragma unroll
    for (int kt = 0; kt < 2; ++kt)
        #pragma unroll
        for (int mt = 0; mt < 2; ++mt)
            aw1[kt][mt] = *(const f16x8*)(w1h + (mt * 16 + lr) * 64 + kt * 32 + lk * 8);
    f16x8 aw2 = *(const f16x8*)(w2h + lr * 32 + lk * 8);
    f32x4 bias1f[2];
    #pragma unroll
    for (int mt = 0; mt < 2; ++mt) {
        float4 bv = *(const float4*)(b1 + mt * 16 + lk * 4);
        bias1f[mt] = f32x4{bv.x, bv.y, bv.z, bv.w};
    }
    float4 b2vv = *(const float4*)b2;
    const f32x4 c2init = (lk == 0) ? f32x4{b2vv.x, b2vv.y, b2vv.z, b2vv.w} : f32x4{0.f, 0.f, 0.f, 0.f};

    char* buf_cur = lds + wid * (2 * BUFB);
    char* buf_nxt = buf_cur + BUFB;

    int tile = blockIdx.x;

    // ---- prologue: stage tile0; seg for tile0 AND tile1 (depth-2 pipeline) ----
    stage_attr(node_attr, tile * MT + wid * WN, lim, buf_cur, lane);
    int s0, s1, n0, n1;
    {
        int wb = tile * MT + wid * WN;
        if (USE_SEG) { s0 = seg_arr[wb + lr]; s1 = seg_arr[wb + 16 + lr]; }
        else { s0 = ubound(gptr, B + 1, wb + lr); s1 = ubound(gptr, B + 1, wb + 16 + lr); }
        int t1 = tile + stride; if (t1 >= ntiles) t1 = tile;
        int wb1 = t1 * MT + wid * WN;
        if (USE_SEG) { n0 = seg_arr[wb1 + lr]; n1 = seg_arr[wb1 + 16 + lr]; }
        else { n0 = ubound(gptr, B + 1, wb1 + lr); n1 = ubound(gptr, B + 1, wb1 + 16 + lr); }
    }

    while (tile < ntiles) {
        const int wb = tile * MT + wid * WN;
        int tp1 = tile + stride;     if (tp1 >= ntiles) tp1 = tile;   // next tile (stage target)
        int tp2 = tile + 2 * stride; if (tp2 >= ntiles) tp2 = tile;   // seg prefetch target

        // ---- A: current tile gathers (10 VMEM); seg in regs since 2 iters ago -> no drain ----
        float is0 = inv_std_g[s0];
        float is1 = inv_std_g[s1];
        f32x4 acc0[4][2];
        #pragma unroll
        for (int mt = 0; mt < 4; ++mt) {
            acc0[mt][0] = *(const f32x4*)(emb0 + s0 * 64 + mt * 16 + lk * 4);
            acc0[mt][1] = *(const f32x4*)(emb0 + s1 * 64 + mt * 16 + lk * 4);
        }

        // ---- B: stage tile+1 -> buf_nxt (6 VMEM, zero VGPR, in flight all iter) ----
        stage_attr(node_attr, tp1 * MT + wid * WN, lim, buf_nxt, lane);

        // ---- C: seg for tile+2 (2 VMEM, consumed two iterations from now) ----
        int m0, m1;
        {
            int wb2 = tp2 * MT + wid * WN;
            if (USE_SEG) { m0 = seg_arr[wb2 + lr]; m1 = seg_arr[wb2 + 16 + lr]; }
            else { m0 = ubound(gptr, B + 1, wb2 + lr); m1 = ubound(gptr, B + 1, wb2 + 16 + lr); }
        }

        // ---- guarantee prev iter's stage of buf_cur landed: 20 loads issued since it ----
        asm volatile("s_waitcnt vmcnt(20)" ::: "memory");
        __builtin_amdgcn_sched_barrier(0);

        // ---- cvt: read this tile's attr from buf_cur (f32) -> L0 B-fragments (f16) ----
        union u8 { fp16x2 h2[4]; f16x8 v; };
        f16x8 bf[2][2];
        #pragma unroll
        for (int nt = 0; nt < 2; ++nt) {
            const float4* rowp = (const float4*)(buf_cur + (nt * 16 + lr) * (FEAT * 4));
            float4 a = rowp[lk * 2];
            float4 b = rowp[lk * 2 + 1];
            float4 c = make_float4(0.f, 0.f, 0.f, 0.f);
            float4 d = make_float4(0.f, 0.f, 0.f, 0.f);
            if (lk == 0) { c = rowp[8]; d = rowp[9]; }        // feats 32..39
            else if (lk == 1) { c = rowp[10]; }               // feats 40..43 (44..47 zero)
            u8 f0, f1;
            f0.h2[0] = __builtin_amdgcn_cvt_pkrtz(a.x, a.y);
            f0.h2[1] = __builtin_amdgcn_cvt_pkrtz(a.z, a.w);
            f0.h2[2] = __builtin_amdgcn_cvt_pkrtz(b.x, b.y);
            f0.h2[3] = __builtin_amdgcn_cvt_pkrtz(b.z, b.w);
            f1.h2[0] = __builtin_amdgcn_cvt_pkrtz(c.x, c.y);
            f1.h2[1] = __builtin_amdgcn_cvt_pkrtz(c.z, c.w);
            f1.h2[2] = __builtin_amdgcn_cvt_pkrtz(d.x, d.y);
            f1.h2[3] = __builtin_amdgcn_cvt_pkrtz(d.z, d.w);
            bf[nt][0] = f0.v;
            bf[nt][1] = f1.v;
        }

        // ---- layer 0: D^T[64 out][32 nodes], K=64, C-init = emb0 (wait = vmcnt(8)) ----
        #pragma unroll
        for (int kt = 0; kt < 2; ++kt)
            #pragma unroll
            for (int mt = 0; mt < 4; ++mt)
                #pragma unroll
                for (int nt = 0; nt < 2; ++nt)
                    acc0[mt][nt] = __builtin_amdgcn_mfma_f32_16x16x32_f16(aw0[kt][mt], bf[nt][kt], acc0[mt][nt], 0, 0, 0);

        // ---- epilogue 0 -> A1 in buf_cur [0,4096) (attr consumed; same-wave DS order) ----
        #pragma unroll
        for (int mt = 0; mt < 4; ++mt)
            #pragma unroll
            for (int nt = 0; nt < 2; ++nt) {
                int j = nt * 16 + lr;
                union { fp16x2 h2[2]; uint2 u; } p;
                p.h2[0] = __builtin_amdgcn_cvt_pkrtz(swishf(acc0[mt][nt][0]), swishf(acc0[mt][nt][1]));
                p.h2[1] = __builtin_amdgcn_cvt_pkrtz(swishf(acc0[mt][nt][2]), swishf(acc0[mt][nt][3]));
                int addr = j * 128 + (mt * 16 + lk * 4) * 2;
                *(uint2*)(buf_cur + (addr ^ ((j & 7) << 4))) = p.u;
            }

        // ---- layer 1: D^T[32 out][32 nodes], K=64, C-init = b1 ----
        f32x4 acc1[2][2];
        #pragma unroll
        for (int mt = 0; mt < 2; ++mt) { acc1[mt][0] = bias1f[mt]; acc1[mt][1] = bias1f[mt]; }
        #pragma unroll
        for (int kt = 0; kt < 2; ++kt) {
            f16x8 bx[2];
            #pragma unroll
            for (int nt = 0; nt < 2; ++nt) {
                int j    = nt * 16 + lr;
                int addr = j * 128 + kt * 64 + lk * 16;
                bx[nt] = *(const f16x8*)(buf_cur + (addr ^ ((j & 7) << 4)));
            }
            #pragma unroll
            for (int mt = 0; mt < 2; ++mt)
                #pragma unroll
                for (int nt = 0; nt < 2; ++nt)
                    acc1[mt][nt] = __builtin_amdgcn_mfma_f32_16x16x32_f16(aw1[kt][mt], bx[nt], acc1[mt][nt], 0, 0, 0);
        }

        // ---- epilogue 1 -> A2 in buf_cur [4096,6144), 64B rows ----
        #pragma unroll
        for (int mt = 0; mt < 2; ++mt)
            #pragma unroll
            for (int nt = 0; nt < 2; ++nt) {
                int j = nt * 16 + lr;
                union { fp16x2 h2[2]; uint2 u; } p;
                p.h2[0] = __builtin_amdgcn_cvt_pkrtz(swishf(acc1[mt][nt][0]), swishf(acc1[mt][nt][1]));
                p.h2[1] = __builtin_amdgcn_cvt_pkrtz(swishf(acc1[mt][nt][2]), swishf(acc1[mt][nt][3]));
                int addr = 4096 + j * 64 + (mt * 16 + lk * 4) * 2;
                *(uint2*)(buf_cur + (addr ^ ((j & 3) << 4))) = p.u;
            }

        // ---- layer 2 + direct global store ----
        f32x4 acc2[2] = {c2init, c2init};
        #pragma unroll
        for (int nt = 0; nt < 2; ++nt) {
            int j    = nt * 16 + lr;
            int addr = 4096 + j * 64 + lk * 16;
            f16x8 bx = *(const f16x8*)(buf_cur + (addr ^ ((j & 3) << 4)));
            acc2[nt] = __builtin_amdgcn_mfma_f32_16x16x32_f16(aw2, bx, acc2[nt], 0, 0, 0);
        }
        if (lk == 0) {
            #pragma unroll
            for (int nt = 0; nt < 2; ++nt) {
                int j = nt * 16 + lr;
                float is = nt ? is1 : is0;
                float4 o;
                o.x = swishf(acc2[nt][0]) * is;
                o.y = swishf(acc2[nt][1]) * is;
                o.z = swishf(acc2[nt][2]) * is;
                o.w = swishf(acc2[nt][3]) * is;
                *(float4*)(out + (size_t)(wb + j) * 4) = o;
            }
        }

        // ---- rotate pipeline ----
        { char* tmp = buf_cur; buf_cur = buf_nxt; buf_nxt = tmp; }
        s0 = n0; s1 = n1; n0 = m0; n1 = m1;
        tile += stride;
    }
}

// ---------------- launch ----------------
extern "C" void kernel_launch(void* const* d_in, const int* in_sizes, int n_in,
                              void* d_out, int out_size, void* d_ws, size_t ws_size,
                              hipStream_t stream) {
    const float* node_attr = (const float*)d_in[0];
    const float* t_arr     = (const float*)d_in[1];
    const int*   gptr      = (const int*)d_in[2];
    const float* W_f       = (const float*)d_in[3];
    const float* embed_w   = (const float*)d_in[4];
    const float* embed_b   = (const float*)d_in[5];
    const float* w0        = (const float*)d_in[6];
    const float* b0        = (const float*)d_in[7];
    const float* w1        = (const float*)d_in[8];
    const float* b1        = (const float*)d_in[9];
    const float* w2        = (const float*)d_in[10];
    const float* b2        = (const float*)d_in[11];
    float* out = (float*)d_out;

    const int N = in_sizes[0] / FEAT;
    const int B = in_sizes[2] - 1;
    const int ntiles = N / MT;
    const int nbytes_attr = in_sizes[0] * 4;

    char* ws = (char*)d_ws;
    size_t off = 0;
    float*    emb0    = (float*)(ws + off); off += (size_t)B * 64 * sizeof(float);
    off = (off + 1023) & ~(size_t)1023;
    float*    inv_std = (float*)(ws + off); off += (size_t)B * sizeof(float);
    off = (off + 1023) & ~(size_t)1023;
    _Float16* w0h = (_Float16*)(ws + off);  off += 64 * 64 * sizeof(_Float16);
    _Float16* w1h = (_Float16*)(ws + off);  off += 32 * 64 * sizeof(_Float16);
    _Float16* w2h = (_Float16*)(ws + off);  off += 16 * 32 * sizeof(_Float16);
    off = (off + 1023) & ~(size_t)1023;
    int* seg = (int*)(ws + off);
    size_t need_with_seg = off + (size_t)N * sizeof(int);
    bool use_seg = (ws_size >= need_with_seg);

    const int grid = (ntiles < NBLK) ? ntiles : NBLK;

    prep_all<<<B + 1, 128, 0, stream>>>(t_arr, W_f, embed_w, embed_b, w0, b0, w1, w2,
                                        gptr, seg, use_seg ? 1 : 0,
                                        emb0, inv_std, w0h, w1h, w2h, B);
    if (use_seg) {
        scorenet_main<true><<<grid, 256, 0, stream>>>(node_attr, gptr, B, seg, emb0, inv_std,
                                                      w0h, w1h, w2h, b1, b2, out, ntiles, nbytes_attr);
    } else {
        scorenet_main<false><<<grid, 256, 0, stream>>>(node_attr, gptr, B, seg, emb0, inv_std,
                                                       w0h, w1h, w2h, b1, b2, out, ntiles, nbytes_attr);
    }
}